// Round 14
// baseline (92.050 us; speedup 1.0000x reference)
//
#include <hip/hip_runtime.h>
#include <cstddef>

#define B_  2
#define T_  2048
#define C_  1024
#define H_  16
#define D_  64
#define M_  64
#define NC_ 32
#define CH_ 64

typedef __attribute__((ext_vector_type(8))) short bf16x8;
typedef __attribute__((ext_vector_type(4))) float f32x4;

__device__ __forceinline__ ushort f2bf(float f) {
    union { float f; unsigned u; } v; v.f = f;
    unsigned r = v.u + 0x7FFF + ((v.u >> 16) & 1);   // RNE
    return (ushort)(r >> 16);
}
__device__ __forceinline__ float bf2f(ushort u) {
    union { unsigned u; float f; } x; x.u = ((unsigned)u) << 16; return x.f;
}

__device__ __forceinline__ void gld_lds16(const ushort* g, ushort* lds) {
    __builtin_amdgcn_global_load_lds(
        (const __attribute__((address_space(1))) unsigned int*)g,
        (__attribute__((address_space(3))) unsigned int*)lds,
        16, 0, 0);
}

// fragment read from a swizzled [R][64] bf16 LDS tile (128B rows, byte ^= (row&7)<<4)
__device__ __forceinline__ bf16x8 frag_ld(const ushort* lds, int row16, int k0, int lane) {
    int r = row16 + (lane & 15);
    int byte = ((k0 * 2) + ((lane >> 4) << 4)) ^ ((r & 7) << 4);
    return *(const bf16x8*)((const char*)lds + r * 128 + byte);
}

#define VMCNT(n) asm volatile("s_waitcnt vmcnt(" #n ")" ::: "memory")
#define BAR() do { __builtin_amdgcn_s_barrier(); __builtin_amdgcn_sched_barrier(0); } while (0)

// ================= fused prep: weight combine + casts + bias =================
#define SEG1_ 256
#define SEG2_ 512
#define SEG3_ 1536
#define SEG4_ 1792
#define NPREP_ 1804

__global__ __launch_bounds__(256) void prep_all(
    const float* __restrict__ x, const float* __restrict__ Wqkv,
    const float* __restrict__ bqkv, const float* __restrict__ Wout,
    const float* __restrict__ proj,
    ushort* __restrict__ Wbt, ushort* __restrict__ xbf,
    ushort* __restrict__ WoutBf, float* __restrict__ bbig)
{
    __shared__ float Ws[64 * 128];
    __shared__ float Ps[64 * 64];
    const int blk = blockIdx.x, t = threadIdx.x;
    if (blk < SEG1_) {
        const int sel = blk >> 7, h = (blk >> 3) & 15, cc = blk & 7;
        const int rowbase = sel * 1024 + h * 64;
        {
            const int r0 = t >> 5, cq = t & 31;
#pragma unroll
            for (int k = 0; k < 8; ++k) {
                int r = r0 + 8 * k;
                *(float4*)&Ws[r * 128 + cq * 4] =
                    *(const float4*)&Wqkv[(size_t)(rowbase + r) * 1024 + cc * 128 + cq * 4];
            }
        }
#pragma unroll
        for (int k = 0; k < 4; ++k) {
            int i4 = t + 256 * k;
            *(float4*)&Ps[i4 * 4] = *(const float4*)&proj[h * 4096 + i4 * 4];
        }
        __syncthreads();
#pragma unroll
        for (int k = 0; k < 2; ++k) {
            int id = t + 256 * k;
            int m4 = id >> 5, c4 = id & 31;
            float4 a0 = {0.f,0.f,0.f,0.f}, a1 = a0, a2 = a0, a3 = a0;
            for (int d = 0; d < 64; ++d) {
                float4 w = *(const float4*)&Ws[d * 128 + c4 * 4];
                float4 p = *(const float4*)&Ps[d * 64 + m4 * 4];
                a0.x += p.x*w.x; a0.y += p.x*w.y; a0.z += p.x*w.z; a0.w += p.x*w.w;
                a1.x += p.y*w.x; a1.y += p.y*w.y; a1.z += p.y*w.z; a1.w += p.y*w.w;
                a2.x += p.z*w.x; a2.y += p.z*w.y; a2.z += p.z*w.z; a2.w += p.z*w.w;
                a3.x += p.w*w.x; a3.y += p.w*w.y; a3.z += p.w*w.z; a3.w += p.w*w.w;
            }
            size_t obase = (size_t)(rowbase + m4 * 4) * 1024 + cc * 128 + c4 * 4;
            ushort4 o0 = { f2bf(a0.x), f2bf(a0.y), f2bf(a0.z), f2bf(a0.w) };
            ushort4 o1 = { f2bf(a1.x), f2bf(a1.y), f2bf(a1.z), f2bf(a1.w) };
            ushort4 o2 = { f2bf(a2.x), f2bf(a2.y), f2bf(a2.z), f2bf(a2.w) };
            ushort4 o3 = { f2bf(a3.x), f2bf(a3.y), f2bf(a3.z), f2bf(a3.w) };
            *(ushort4*)&Wbt[obase]          = o0;
            *(ushort4*)&Wbt[obase + 1024]   = o1;
            *(ushort4*)&Wbt[obase + 2048]   = o2;
            *(ushort4*)&Wbt[obase + 3072]   = o3;
        }
    } else if (blk < SEG2_) {
        int bo = blk - SEG1_;
#pragma unroll
        for (int pass = 0; pass < 4; ++pass) {
            int i4 = bo * 1024 + pass * 256 + t;
            float4 v = ((const float4*)Wqkv)[524288 + i4];
            ushort4 o = { f2bf(v.x), f2bf(v.y), f2bf(v.z), f2bf(v.w) };
            ((ushort4*)(Wbt + 2097152))[i4] = o;
        }
    } else if (blk < SEG3_) {
        int bo = blk - SEG2_;
#pragma unroll
        for (int pass = 0; pass < 4; ++pass) {
            int i4 = bo * 1024 + pass * 256 + t;
            float4 v = ((const float4*)x)[i4];
            ushort4 o = { f2bf(v.x), f2bf(v.y), f2bf(v.z), f2bf(v.w) };
            ((ushort4*)xbf)[i4] = o;
        }
    } else if (blk < SEG4_) {
        int bo = blk - SEG3_;
#pragma unroll
        for (int pass = 0; pass < 4; ++pass) {
            int i4 = bo * 1024 + pass * 256 + t;
            float4 v = ((const float4*)Wout)[i4];
            ushort4 o = { f2bf(v.x), f2bf(v.y), f2bf(v.z), f2bf(v.w) };
            ((ushort4*)WoutBf)[i4] = o;
        }
    } else {
        int j = (blk - SEG4_) * 256 + t;
        if (j < 2048) {
            int sel = j >> 10, hm = j & 1023, h = hm >> 6, m = hm & 63;
            const float* b = bqkv + sel * C_ + h * D_;
            const float* p = proj + (size_t)h * D_ * M_ + m;
            float acc = 0.f;
#pragma unroll 8
            for (int d = 0; d < D_; ++d) acc += b[d] * p[(size_t)d * M_];
            bbig[j] = acc;
        } else {
            bbig[j] = bqkv[j];
        }
    }
}

// ================= GEMM1: 256x256, BK=64, counted-vmcnt prefetch (never drain in loop) =================
// 512 thr, 8 waves (2Mx4N), wave out 128x64, acc[8][4]. LDS 128KB dbuf.
// Per tile: BAR -> issue 8 prefetch -> VMCNT(8) -> BAR -> 4 quadrant phases (64 MFMA/wave).
__device__ __forceinline__ void g1_stage(const ushort* __restrict__ G, ushort* buf,
                                         int base0, int K, int kcol, int unit, int w, int lane) {
    int rb = unit * 64 + w * 8;
    int r  = rb + (lane >> 3);
    int c  = (lane & 7) * 8;
    int cs = c ^ ((r & 7) << 3);
    gld_lds16(G + (size_t)(base0 + r) * K + kcol + cs, buf + rb * 64);
}

__device__ __forceinline__ void g1_lda(const ushort* Abuf, bf16x8 (&a)[4][2], int row0, int lane) {
#pragma unroll
    for (int i = 0; i < 4; ++i)
#pragma unroll
        for (int ks = 0; ks < 2; ++ks)
            a[i][ks] = frag_ld(Abuf, row0 + i * 16, ks * 32, lane);
}
__device__ __forceinline__ void g1_ldb(const ushort* Bbuf, bf16x8 (&b)[2][2], int row0, int lane) {
#pragma unroll
    for (int j = 0; j < 2; ++j)
#pragma unroll
        for (int ks = 0; ks < 2; ++ks)
            b[j][ks] = frag_ld(Bbuf, row0 + j * 16, ks * 32, lane);
}
__device__ __forceinline__ void g1_mfma(f32x4 (&acc)[8][4], const bf16x8 (&a)[4][2],
                                        const bf16x8 (&b)[2][2], int Mh, int Nh) {
    __builtin_amdgcn_s_setprio(1);
#pragma unroll
    for (int ks = 0; ks < 2; ++ks)
#pragma unroll
        for (int i = 0; i < 4; ++i)
#pragma unroll
            for (int j = 0; j < 2; ++j)
                acc[Mh * 4 + i][Nh * 2 + j] = __builtin_amdgcn_mfma_f32_16x16x32_bf16(
                    a[i][ks], b[j][ks], acc[Mh * 4 + i][Nh * 2 + j], 0, 0, 0);
    __builtin_amdgcn_s_setprio(0);
}

__global__ __launch_bounds__(512, 2) void gemm1_256(
    const ushort* __restrict__ A, const ushort* __restrict__ Bt,
    const float* __restrict__ bias, ushort* __restrict__ Cout,
    int M, int N, int K, int reluLimit)
{
    __shared__ __align__(16) ushort lds[65536];      // 128 KiB

    const int tid = threadIdx.x, w = tid >> 6, lane = tid & 63;
    const int m0 = blockIdx.y * 256, n0 = blockIdx.x * 256;
    const int wr = (w >> 2) * 128, wc = (w & 3) * 64;
    f32x4 acc[8][4] = {};
    const int NT = K / 64;

    // prologue: issue tile-0 loads into buffer 0 (8 loads/thread)
#pragma unroll
    for (int u = 0; u < 4; ++u) g1_stage(A,  lds,         m0, K, 0, u, w, lane);
#pragma unroll
    for (int u = 0; u < 4; ++u) g1_stage(Bt, lds + 32768, n0, K, 0, u, w, lane);

    for (int kt = 0; kt < NT; ++kt) {
        const int p = kt & 1;
        ushort* Acur = lds + p * 16384;
        ushort* Bcur = lds + 32768 + p * 16384;
        ushort* Anxt = lds + (p ^ 1) * 16384;
        ushort* Bnxt = lds + 32768 + (p ^ 1) * 16384;
        const int kc1 = (kt + 1) * 64;
        bf16x8 a0[4][2], a1[4][2], b0[2][2], b1[2][2];

        BAR();                                 // all waves done reading buf p^1 (tile kt-1)
        if (kt + 1 < NT) {
            // issue ALL 8 prefetch loads up-front; they fly across the whole tile
#pragma unroll
            for (int u = 0; u < 4; ++u) g1_stage(A,  Anxt, m0, K, kc1, u, w, lane);
#pragma unroll
            for (int u = 0; u < 4; ++u) g1_stage(Bt, Bnxt, n0, K, kc1, u, w, lane);
            VMCNT(8);                          // wait only for tile-kt's 8 loads (oldest)
        } else {
            VMCNT(0);                          // last tile: drain
        }
        BAR();                                 // tile-kt data visible to all waves

        // phase 0: (Mh0, Nh0)
        g1_lda(Acur, a0, wr, lane);
        g1_ldb(Bcur, b0, wc, lane);
        g1_mfma(acc, a0, b0, 0, 0);
        // phase 1: (Mh0, Nh1)
        g1_ldb(Bcur, b1, wc + 32, lane);
        g1_mfma(acc, a0, b1, 0, 1);
        // phase 2: (Mh1, Nh0)
        g1_lda(Acur, a1, wr + 64, lane);
        g1_mfma(acc, a1, b0, 1, 0);
        // phase 3: (Mh1, Nh1)
        g1_mfma(acc, a1, b1, 1, 1);
    }

    const int crow = (lane >> 4) * 4, ccol = lane & 15;
#pragma unroll
    for (int nj = 0; nj < 4; ++nj) {
        int col = n0 + wc + nj * 16 + ccol;
        float bv = bias[col];
        bool rl = col < reluLimit;
#pragma unroll
        for (int mi = 0; mi < 8; ++mi) {
#pragma unroll
            for (int rr = 0; rr < 4; ++rr) {
                int row = m0 + wr + mi * 16 + crow + rr;
                float v = acc[mi][nj][rr] + bv;
                if (rl) v = fmaxf(v, 0.f);
                Cout[(size_t)row * N + col] = f2bf(v);
            }
        }
    }
}

// ================= GEMM2: 128x128 8-phase (2 blocks/CU), fragment-hoisted =================
__device__ __forceinline__ void g2_stage_G0(const ushort* __restrict__ Ag, const ushort* __restrict__ Bg,
                                            ushort* Abuf, ushort* Bbuf,
                                            int m0, int n0, int K, int kcol, int w, int lane) {
    const int l8 = lane >> 3, lc = (lane & 7) * 8;
    {
        int rbase = (w < 4) ? w * 8 : 64 + (w - 4) * 8;
        int r = rbase + l8;
        int cs = lc ^ ((r & 7) << 3);
        gld_lds16(Ag + (size_t)(m0 + r) * K + kcol + cs, Abuf + rbase * 64);
    }
    {
        int rbase = (w >> 1) * 32 + (w & 1) * 8;
        int r = rbase + l8;
        int cs = lc ^ ((r & 7) << 3);
        gld_lds16(Bg + (size_t)(n0 + r) * K + kcol + cs, Bbuf + rbase * 64);
    }
}

__device__ __forceinline__ void g2_stage_G1(const ushort* __restrict__ Ag, const ushort* __restrict__ Bg,
                                            ushort* Abuf, ushort* Bbuf,
                                            int m0, int n0, int K, int kcol, int w, int lane) {
    const int l8 = lane >> 3, lc = (lane & 7) * 8;
    {
        int rbase = 16 + (w >> 1) * 32 + (w & 1) * 8;
        int r = rbase + l8;
        int cs = lc ^ ((r & 7) << 3);
        gld_lds16(Bg + (size_t)(n0 + r) * K + kcol + cs, Bbuf + rbase * 64);
    }
    {
        int rbase = (w < 4) ? 32 + w * 8 : 96 + (w - 4) * 8;
        int r = rbase + l8;
        int cs = lc ^ ((r & 7) << 3);
        gld_lds16(Ag + (size_t)(m0 + r) * K + kcol + cs, Abuf + rbase * 64);
    }
}

__device__ __forceinline__ void lda2(const ushort* Abuf, bf16x8 (&a)[2][2], int wr, int Mh, int lane) {
#pragma unroll
    for (int i = 0; i < 2; ++i)
#pragma unroll
        for (int ks = 0; ks < 2; ++ks)
            a[i][ks] = frag_ld(Abuf, wr + Mh * 32 + i * 16, ks * 32, lane);
}
__device__ __forceinline__ void g2_ldb(const ushort* Bbuf, bf16x8 (&b)[2], int wc, int Nh, int lane) {
#pragma unroll
    for (int ks = 0; ks < 2; ++ks)
        b[ks] = frag_ld(Bbuf, wc + Nh * 16, ks * 32, lane);
}
__device__ __forceinline__ void g2_mfma(f32x4 (&acc)[4][2], const bf16x8 (&a)[2][2],
                                        const bf16x8 (&b)[2], int Mh, int Nh) {
    __builtin_amdgcn_s_setprio(1);
#pragma unroll
    for (int ks = 0; ks < 2; ++ks)
#pragma unroll
        for (int i = 0; i < 2; ++i)
            acc[Mh * 2 + i][Nh] = __builtin_amdgcn_mfma_f32_16x16x32_bf16(
                a[i][ks], b[ks], acc[Mh * 2 + i][Nh], 0, 0, 0);
    __builtin_amdgcn_s_setprio(0);
}

__global__ __launch_bounds__(512, 4) void gemm2_8phase(
    const ushort* __restrict__ A, const ushort* __restrict__ Bt,
    const float* __restrict__ bias, float* __restrict__ Cout,
    int M, int N, int K)
{
    __shared__ __align__(16) ushort lds[32768];      // 64 KiB

    const int tid = threadIdx.x, w = tid >> 6, lane = tid & 63;
    const int m0 = blockIdx.y * 128, n0 = blockIdx.x * 128;
    const int wr = (w >> 2) * 64, wc = (w & 3) * 32;
    f32x4 acc[4][2] = {};
    const int NT = K / 64;

    g2_stage_G0(A, Bt, lds, lds + 16384, m0, n0, K, 0, w, lane);
    g2_stage_G1(A, Bt, lds, lds + 16384, m0, n0, K, 0, w, lane);

    for (int kt = 0; kt < NT - 1; ++kt) {
        const int p = kt & 1;
        ushort* Acur = lds + p * 8192;
        ushort* Anxt = lds + (p ^ 1) * 8192;
        ushort* Bcur = lds + 16384 + p * 8192;
        ushort* Bnxt = lds + 16384 + (p ^ 1) * 8192;
        const int kc1 = (kt + 1) * 64;
        bf16x8 a[2][2], a2[2][2], b[2], b2[2];
        VMCNT(2); BAR();
        g2_stage_G0(A, Bt, Anxt, Bnxt, m0, n0, K, kc1, w, lane);
        lda2(Acur, a, wr, 0, lane);
        g2_ldb(Bcur, b, wc, 0, lane);
        g2_mfma(acc, a, b, 0, 0);
        VMCNT(3); BAR();
        g2_ldb(Bcur, b2, wc, 1, lane);
        g2_mfma(acc, a, b2, 0, 1);
        VMCNT(2); BAR();
        g2_stage_G1(A, Bt, Anxt, Bnxt, m0, n0, K, kc1, w, lane);
        lda2(Acur, a2, wr, 1, lane);
        g2_mfma(acc, a2, b, 1, 0);
        g2_mfma(acc, a2, b2, 1, 1);
    }
    {
        const int p = (NT - 1) & 1;
        ushort* Acur = lds + p * 8192;
        ushort* Bcur = lds + 16384 + p * 8192;
        bf16x8 a[2][2], a2[2][2], b[2], b2[2];
        VMCNT(2); BAR();
        lda2(Acur, a, wr, 0, lane);
        g2_ldb(Bcur, b, wc, 0, lane);
        g2_mfma(acc, a, b, 0, 0);
        VMCNT(1); BAR();
        g2_ldb(Bcur, b2, wc, 1, lane);
        g2_mfma(acc, a, b2, 0, 1);
        VMCNT(0); BAR();
        lda2(Acur, a2, wr, 1, lane);
        g2_mfma(acc, a2, b, 1, 0);
        g2_mfma(acc, a2, b2, 1, 1);
    }

    const int crow = (lane >> 4) * 4, ccol = lane & 15;
#pragma unroll
    for (int nj = 0; nj < 2; ++nj) {
        int col = n0 + wc + nj * 16 + ccol;
        float bv = bias[col];
#pragma unroll
        for (int mi = 0; mi < 4; ++mi) {
#pragma unroll
            for (int rr = 0; rr < 4; ++rr) {
                int row = m0 + wr + mi * 16 + crow + rr;
                Cout[(size_t)row * N + col] = acc[mi][nj][rr] + bv;
            }
        }
    }
}

// ---------------- chunk_kv: transpose K,V per chunk; St(bf16) = Vt@Kt^T; sK sums ----------------
__global__ __launch_bounds__(256) void chunk_kv_mfma(
    const ushort* __restrict__ out1, ushort* __restrict__ VtG,
    ushort* __restrict__ StB, float* __restrict__ sks)
{
    __shared__ unsigned Tl[64 * 76];
    __shared__ ushort Ktb[64 * 64];
    __shared__ ushort Vtb[64 * 64];
    __shared__ float skp[4][64];
    const int blk = blockIdx.x, c = blk & 31, bh = blk >> 5;
    const int b = bh >> 4, h = bh & 15, t0 = c * CH_;
    const int tid = threadIdx.x, wave = tid >> 6, lane = tid & 63;
    const ushort* kg = out1 + (size_t)(b * T_ + t0) * 3072 + C_ + h * D_;
    const ushort* vg = kg + C_;

#pragma unroll
    for (int it = 0; it < 2; ++it) {
        int i = tid + it * 256, r = i >> 3, sl = i & 7;
        bf16x8 v = *(const bf16x8*)(kg + (size_t)r * 3072 + sl * 8);
        unsigned* dst = &Tl[r * 76 + sl * 8];
        uint4 w0 = { (ushort)v[0], (ushort)v[1], (ushort)v[2], (ushort)v[3] };
        uint4 w1 = { (ushort)v[4], (ushort)v[5], (ushort)v[6], (ushort)v[7] };
        *(uint4*)dst = w0;
        *(uint4*)(dst + 4) = w1;
    }
    __syncthreads();
    {
        int m = tid >> 2, tc = tid & 3;
        bf16x8 va, vb;
        float s = 0.f;
#pragma unroll
        for (int k = 0; k < 8; ++k) {
            ushort u = (ushort)Tl[(tc * 16 + k) * 76 + m];
            va[k] = (short)u; s += bf2f(u);
        }
#pragma unroll
        for (int k = 0; k < 8; ++k) {
            ushort u = (ushort)Tl[(tc * 16 + 8 + k) * 76 + m];
            vb[k] = (short)u; s += bf2f(u);
        }
        skp[tc][m] = s;
        int b0 = (tc * 32) ^ ((m & 7) << 4);
        int b1 = (tc * 32 + 16) ^ ((m & 7) << 4);
        *(bf16x8*)((char*)Ktb + m * 128 + b0) = va;
        *(bf16x8*)((char*)Ktb + m * 128 + b1) = vb;
    }
    __syncthreads();
#pragma unroll
    for (int it = 0; it < 2; ++it) {
        int i = tid + it * 256, r = i >> 3, sl = i & 7;
        bf16x8 v = *(const bf16x8*)(vg + (size_t)r * 3072 + sl * 8);
        unsigned* dst = &Tl[r * 76 + sl * 8];
        uint4 w0 = { (ushort)v[0], (ushort)v[1], (ushort)v[2], (ushort)v[3] };
        uint4 w1 = { (ushort)v[4], (ushort)v[5], (ushort)v[6], (ushort)v[7] };
        *(uint4*)dst = w0;
        *(uint4*)(dst + 4) = w1;
    }
    __syncthreads();
    {
        int d = tid >> 2, tc = tid & 3;
        bf16x8 va, vb;
#pragma unroll
        for (int k = 0; k < 8; ++k) va[k] = (short)(ushort)Tl[(tc * 16 + k) * 76 + d];
#pragma unroll
        for (int k = 0; k < 8; ++k) vb[k] = (short)(ushort)Tl[(tc * 16 + 8 + k) * 76 + d];
        int b0 = (tc * 32) ^ ((d & 7) << 4);
        int b1 = (tc * 32 + 16) ^ ((d & 7) << 4);
        *(bf16x8*)((char*)Vtb + d * 128 + b0) = va;
        *(bf16x8*)((char*)Vtb + d * 128 + b1) = vb;
        ushort* og = VtG + (size_t)blk * 4096 + d * 64 + tc * 16;
        *(bf16x8*)og = va;
        *(bf16x8*)(og + 8) = vb;
    }
    __syncthreads();
    const int wr = wave * 16, g = lane >> 4, ccol = lane & 15;
    f32x4 acc[4] = {};
#pragma unroll
    for (int k0 = 0; k0 < 64; k0 += 32) {
        bf16x8 av = frag_ld(Vtb, wr, k0, lane);
#pragma unroll
        for (int j = 0; j < 4; ++j)
            acc[j] = __builtin_amdgcn_mfma_f32_16x16x32_bf16(av, frag_ld(Ktb, j * 16, k0, lane), acc[j], 0, 0, 0);
    }
    ushort* stg = StB + (size_t)blk * 4096;
#pragma unroll
    for (int j = 0; j < 4; ++j)
#pragma unroll
        for (int r = 0; r < 4; ++r)
            stg[(wr + g * 4 + r) * 64 + j * 16 + ccol] = f2bf(acc[j][r]);
    if (tid < 64)
        sks[(size_t)blk * 64 + tid] = skp[0][tid] + skp[1][tid] + skp[2][tid] + skp[3][tid];
}

// ---------------- parallel exclusive chunk-prefix scan (St bf16) ----------------
__global__ __launch_bounds__(256) void chunk_scan2(const ushort* __restrict__ StB,
                                                   const float* __restrict__ sks,
                                                   ushort* __restrict__ Sbf,
                                                   ushort* __restrict__ skb) {
    if (blockIdx.x < 512) {
        int id = blockIdx.x * 256 + threadIdx.x;
        int bh = id >> 12, e = id & 4095;
        const ushort* p = StB + (size_t)bh * NC_ * 4096 + e;
        ushort* q = Sbf + (size_t)bh * NC_ * 4096 + e;
        float run = 0.f;
        for (int c = 0; c < NC_; ++c) {
            q[(size_t)c * 4096] = f2bf(run);
            run += bf2f(p[(size_t)c * 4096]);
        }
    } else {
        int id2 = (blockIdx.x - 512) * 256 + threadIdx.x;
        int bh = id2 >> 6, m = id2 & 63;
        const float* p = sks + (size_t)bh * NC_ * 64 + m;
        ushort* q = skb + (size_t)bh * NC_ * 64 + m;
        float run = 0.f;
        for (int c = 0; c < NC_; ++c) {
            q[c * 64] = f2bf(run);
            run += p[c * 64];
        }
    }
}

// ---------------- chunk attention (all-MFMA) ----------------
__global__ __launch_bounds__(256) void chunk_attn_mfma(
    const ushort* __restrict__ out1, const ushort* __restrict__ VtG,
    const ushort* __restrict__ Sbf, const ushort* __restrict__ skb,
    ushort* __restrict__ attnBf)
{
    __shared__ ushort Ql[64 * 64];
    __shared__ ushort Kl[64 * 64];
    __shared__ ushort Vl[64 * 64];
    __shared__ ushort Al[64 * 64];
    __shared__ ushort Sl[80 * 64];
    const int blk = blockIdx.x, c = blk & 31, bh = blk >> 5;
    const int b = bh >> 4, h = bh & 15, t0 = c * CH_;
    const int tid = threadIdx.x, wave = tid >> 6, lane = tid & 63;
    const ushort* qg  = out1 + (size_t)(b * T_ + t0) * 3072 + h * D_;
    const ushort* kg  = qg + C_;
    const ushort* vtg = VtG + (size_t)blk * 4096;
    const ushort* sbg = Sbf + (size_t)blk * 4096;
#pragma unroll
    for (int it = 0; it < 2; ++it) {
        int i = tid + it * 256, r = i >> 3, sl = i & 7;
        int lo = (sl * 16) ^ ((r & 7) << 4);
        *(bf16x8*)((char*)Ql + r * 128 + lo) = *(const bf16x8*)(qg + (size_t)r * 3072 + sl * 8);
        *(bf16x8*)((char*)Kl + r * 128 + lo) = *(const bf16x8*)(kg + (size_t)r * 3072 + sl * 8);
        *(bf16x8*)((char*)Vl + r * 128 + lo) = *(const bf16x8*)(vtg + r * 64 + sl * 8);
        *(bf16x8*)((char*)Sl + r * 128 + lo) = *(const bf16x8*)(sbg + r * 64 + sl * 8);
    }
    if (tid < 8)
        *(bf16x8*)((char*)Sl + 64 * 128 + tid * 16) = *(const bf16x8*)(skb + (size_t)blk * 64 + tid * 8);
    __syncthreads();

    const int wr = wave * 16, g = lane >> 4, ccol = lane & 15;
    f32x4 accA[4] = {};
#pragma unroll
    for (int k0 = 0; k0 < 64; k0 += 32) {
        bf16x8 aq = frag_ld(Ql, wr, k0, lane);
#pragma unroll
        for (int j = 0; j < 4; ++j)
            accA[j] = __builtin_amdgcn_mfma_f32_16x16x32_bf16(aq, frag_ld(Kl, j * 16, k0, lane), accA[j], 0, 0, 0);
    }
    float rsum[4] = {0.f, 0.f, 0.f, 0.f};
#pragma unroll
    for (int j = 0; j < 4; ++j) {
#pragma unroll
        for (int r = 0; r < 4; ++r) {
            int tl = wr + g * 4 + r, sl2 = j * 16 + ccol;
            float v = (sl2 <= tl) ? accA[j][r] : 0.f;
            rsum[r] += v;
            *(ushort*)((char*)Al + tl * 128 + ((sl2 * 2) ^ ((tl & 7) << 4))) = f2bf(v);
        }
    }
#pragma unroll
    for (int r = 0; r < 4; ++r) {
        rsum[r] += __shfl_xor(rsum[r], 1);
        rsum[r] += __shfl_xor(rsum[r], 2);
        rsum[r] += __shfl_xor(rsum[r], 4);
        rsum[r] += __shfl_xor(rsum[r], 8);
    }
    f32x4 accC[4] = {};
    f32x4 accE = {};
#pragma unroll
    for (int k0 = 0; k0 < 64; k0 += 32) {
        bf16x8 aa = frag_ld(Al, wr, k0, lane);
#pragma unroll
        for (int j = 0; j < 4; ++j)
            accC[j] = __builtin_amdgcn_mfma_f32_16x16x32_bf16(aa, frag_ld(Vl, j * 16, k0, lane), accC[j], 0, 0, 0);
    }
#pragma unroll
    for (int k0 = 0; k0 < 64; k0 += 32) {
        bf16x8 aq = frag_ld(Ql, wr, k0, lane);
#pragma unroll
        for (int j = 0; j < 4; ++j)
            accC[j] = __builtin_amdgcn_mfma_f32_16x16x32_bf16(aq, frag_ld(Sl, j * 16, k0, lane), accC[j], 0, 0, 0);
        accE = __builtin_amdgcn_mfma_f32_16x16x32_bf16(aq, frag_ld(Sl, 64, k0, lane), accE, 0, 0, 0);
    }
    ushort* og = attnBf + (size_t)(b * T_ + t0) * C_ + h * D_;
#pragma unroll
    for (int r = 0; r < 4; ++r) {
        float nq = __shfl(accE[r], (lane & 48));
        float inv = 1.f / (nq + rsum[r] + 1e-6f);
        int tl = wr + g * 4 + r;
#pragma unroll
        for (int j = 0; j < 4; ++j)
            og[(size_t)tl * C_ + j * 16 + ccol] = f2bf(accC[j][r] * inv);
    }
}

extern "C" void kernel_launch(void* const* d_in, const int* in_sizes, int n_in,
                              void* d_out, int out_size, void* d_ws, size_t ws_size,
                              hipStream_t stream) {
    (void)in_sizes; (void)n_in; (void)out_size; (void)ws_size;
    const float* x    = (const float*)d_in[0];
    const float* Wqkv = (const float*)d_in[1];
    const float* bqkv = (const float*)d_in[2];
    const float* Wout = (const float*)d_in[3];
    const float* bout = (const float*)d_in[4];
    const float* proj = (const float*)d_in[5];
    float* out = (float*)d_out;
    char* ws = (char*)d_ws;

    ushort* Wbt    = (ushort*)(ws);                 // 6 MB
    ushort* xbf    = (ushort*)(ws + (6ull  << 20)); // 8 MB
    ushort* WoutBf = (ushort*)(ws + (14ull << 20)); // 2 MB
    ushort* attnBf = (ushort*)(ws + (16ull << 20)); // 8 MB
    float*  bbig   = (float*) (ws + (24ull << 20)); // 12 KB
    ushort* out1   = (ushort*)(ws + (25ull << 20)); // 24 MB (bf16 q'|k'|v)
    ushort* VtG    = (ushort*)(ws + (49ull << 20)); // 8 MB
    ushort* StB    = (ushort*)(ws + (57ull << 20)); // 8 MB (bf16)
    ushort* Sbf    = (ushort*)(ws + (65ull << 20)); // 8 MB
    float*  sks    = (float*) (ws + (73ull << 20)); // 256 KB
    ushort* skb    = (ushort*)(ws + (74ull << 20)); // 128 KB

    prep_all<<<NPREP_, 256, 0, stream>>>(x, Wqkv, bqkv, Wout, proj,
                                         Wbt, xbf, WoutBf, bbig);
    gemm1_256<<<dim3(12, 16), 512, 0, stream>>>(xbf, Wbt, bbig, out1,
                                                4096, 3072, 1024, 2048);
    chunk_kv_mfma<<<1024, 256, 0, stream>>>(out1, VtG, StB, sks);
    chunk_scan2<<<520, 256, 0, stream>>>(StB, sks, Sbf, skb);
    chunk_attn_mfma<<<1024, 256, 0, stream>>>(out1, VtG, Sbf, skb, attnBf);
    gemm2_8phase<<<dim3(8, 32), 512, 0, stream>>>(attnBf, WoutBf, bout, out,
                                                  4096, 1024, 1024);
}

// Round 15
// 85.407 us; speedup vs baseline: 1.0778x; 1.0778x over previous
//
#include <hip/hip_runtime.h>
#include <cstddef>

#define B_  2
#define T_  2048
#define C_  1024
#define H_  16
#define D_  64
#define M_  64
#define NC_ 32
#define CH_ 64

typedef __attribute__((ext_vector_type(8))) short bf16x8;
typedef __attribute__((ext_vector_type(4))) float f32x4;

__device__ __forceinline__ ushort f2bf(float f) {
    union { float f; unsigned u; } v; v.f = f;
    unsigned r = v.u + 0x7FFF + ((v.u >> 16) & 1);   // RNE
    return (ushort)(r >> 16);
}
__device__ __forceinline__ float bf2f(ushort u) {
    union { unsigned u; float f; } x; x.u = ((unsigned)u) << 16; return x.f;
}

__device__ __forceinline__ void gld_lds16(const ushort* g, ushort* lds) {
    __builtin_amdgcn_global_load_lds(
        (const __attribute__((address_space(1))) unsigned int*)g,
        (__attribute__((address_space(3))) unsigned int*)lds,
        16, 0, 0);
}

// fragment read from a swizzled [R][64] bf16 LDS tile (128B rows, byte ^= (row&7)<<4)
__device__ __forceinline__ bf16x8 frag_ld(const ushort* lds, int row16, int k0, int lane) {
    int r = row16 + (lane & 15);
    int byte = ((k0 * 2) + ((lane >> 4) << 4)) ^ ((r & 7) << 4);
    return *(const bf16x8*)((const char*)lds + r * 128 + byte);
}

#define VMCNT(n) asm volatile("s_waitcnt vmcnt(" #n ")" ::: "memory")
#define BAR() do { __builtin_amdgcn_s_barrier(); __builtin_amdgcn_sched_barrier(0); } while (0)

// ================= fused prep: weight combine + casts + bias =================
#define SEG1_ 256
#define SEG2_ 512
#define SEG3_ 1536
#define SEG4_ 1792
#define NPREP_ 1804

__global__ __launch_bounds__(256) void prep_all(
    const float* __restrict__ x, const float* __restrict__ Wqkv,
    const float* __restrict__ bqkv, const float* __restrict__ Wout,
    const float* __restrict__ proj,
    ushort* __restrict__ Wbt, ushort* __restrict__ xbf,
    ushort* __restrict__ WoutBf, float* __restrict__ bbig)
{
    __shared__ float Ws[64 * 128];
    __shared__ float Ps[64 * 64];
    const int blk = blockIdx.x, t = threadIdx.x;
    if (blk < SEG1_) {
        const int sel = blk >> 7, h = (blk >> 3) & 15, cc = blk & 7;
        const int rowbase = sel * 1024 + h * 64;
        {
            const int r0 = t >> 5, cq = t & 31;
#pragma unroll
            for (int k = 0; k < 8; ++k) {
                int r = r0 + 8 * k;
                *(float4*)&Ws[r * 128 + cq * 4] =
                    *(const float4*)&Wqkv[(size_t)(rowbase + r) * 1024 + cc * 128 + cq * 4];
            }
        }
#pragma unroll
        for (int k = 0; k < 4; ++k) {
            int i4 = t + 256 * k;
            *(float4*)&Ps[i4 * 4] = *(const float4*)&proj[h * 4096 + i4 * 4];
        }
        __syncthreads();
#pragma unroll
        for (int k = 0; k < 2; ++k) {
            int id = t + 256 * k;
            int m4 = id >> 5, c4 = id & 31;
            float4 a0 = {0.f,0.f,0.f,0.f}, a1 = a0, a2 = a0, a3 = a0;
            for (int d = 0; d < 64; ++d) {
                float4 w = *(const float4*)&Ws[d * 128 + c4 * 4];
                float4 p = *(const float4*)&Ps[d * 64 + m4 * 4];
                a0.x += p.x*w.x; a0.y += p.x*w.y; a0.z += p.x*w.z; a0.w += p.x*w.w;
                a1.x += p.y*w.x; a1.y += p.y*w.y; a1.z += p.y*w.z; a1.w += p.y*w.w;
                a2.x += p.z*w.x; a2.y += p.z*w.y; a2.z += p.z*w.z; a2.w += p.z*w.w;
                a3.x += p.w*w.x; a3.y += p.w*w.y; a3.z += p.w*w.z; a3.w += p.w*w.w;
            }
            size_t obase = (size_t)(rowbase + m4 * 4) * 1024 + cc * 128 + c4 * 4;
            ushort4 o0 = { f2bf(a0.x), f2bf(a0.y), f2bf(a0.z), f2bf(a0.w) };
            ushort4 o1 = { f2bf(a1.x), f2bf(a1.y), f2bf(a1.z), f2bf(a1.w) };
            ushort4 o2 = { f2bf(a2.x), f2bf(a2.y), f2bf(a2.z), f2bf(a2.w) };
            ushort4 o3 = { f2bf(a3.x), f2bf(a3.y), f2bf(a3.z), f2bf(a3.w) };
            *(ushort4*)&Wbt[obase]          = o0;
            *(ushort4*)&Wbt[obase + 1024]   = o1;
            *(ushort4*)&Wbt[obase + 2048]   = o2;
            *(ushort4*)&Wbt[obase + 3072]   = o3;
        }
    } else if (blk < SEG2_) {
        int bo = blk - SEG1_;
#pragma unroll
        for (int pass = 0; pass < 4; ++pass) {
            int i4 = bo * 1024 + pass * 256 + t;
            float4 v = ((const float4*)Wqkv)[524288 + i4];
            ushort4 o = { f2bf(v.x), f2bf(v.y), f2bf(v.z), f2bf(v.w) };
            ((ushort4*)(Wbt + 2097152))[i4] = o;
        }
    } else if (blk < SEG3_) {
        int bo = blk - SEG2_;
#pragma unroll
        for (int pass = 0; pass < 4; ++pass) {
            int i4 = bo * 1024 + pass * 256 + t;
            float4 v = ((const float4*)x)[i4];
            ushort4 o = { f2bf(v.x), f2bf(v.y), f2bf(v.z), f2bf(v.w) };
            ((ushort4*)xbf)[i4] = o;
        }
    } else if (blk < SEG4_) {
        int bo = blk - SEG3_;
#pragma unroll
        for (int pass = 0; pass < 4; ++pass) {
            int i4 = bo * 1024 + pass * 256 + t;
            float4 v = ((const float4*)Wout)[i4];
            ushort4 o = { f2bf(v.x), f2bf(v.y), f2bf(v.z), f2bf(v.w) };
            ((ushort4*)WoutBf)[i4] = o;
        }
    } else {
        int j = (blk - SEG4_) * 256 + t;
        if (j < 2048) {
            int sel = j >> 10, hm = j & 1023, h = hm >> 6, m = hm & 63;
            const float* b = bqkv + sel * C_ + h * D_;
            const float* p = proj + (size_t)h * D_ * M_ + m;
            float acc = 0.f;
#pragma unroll 8
            for (int d = 0; d < D_; ++d) acc += b[d] * p[(size_t)d * M_];
            bbig[j] = acc;
        } else {
            bbig[j] = bqkv[j];
        }
    }
}

// ================= 8-phase pipelined GEMM1 (BM=128, BN=384, BK=64), fragment-hoisted =================
__device__ __forceinline__ void stage_G0(const ushort* __restrict__ Ag, const ushort* __restrict__ Bg,
                                         ushort* Abuf, ushort* Bbuf,
                                         int m0, int n0, int K, int kcol, int w, int lane) {
    const int l8 = lane >> 3, lc = (lane & 7) * 8;
#pragma unroll
    for (int i = 0; i < 4; ++i) {
        int c = w * 4 + i;
        if (c < 8) {
            int fr = (c < 4) ? c * 8 : 64 + (c - 4) * 8;
            int r = fr + l8;
            int cs = lc ^ ((r & 7) << 3);
            gld_lds16(Ag + (size_t)(m0 + r) * K + kcol + cs, Abuf + fr * 64);
        } else {
            int cb = c - 8, g = cb / 6, k8 = cb - g * 6;
            int fr = g * 96 + k8 * 8;
            int r = fr + l8;
            int cs = lc ^ ((r & 7) << 3);
            gld_lds16(Bg + (size_t)(n0 + r) * K + kcol + cs, Bbuf + fr * 64);
        }
    }
}

__device__ __forceinline__ void stage_G1(const ushort* __restrict__ Ag, const ushort* __restrict__ Bg,
                                         ushort* Abuf, ushort* Bbuf,
                                         int m0, int n0, int K, int kcol, int w, int lane) {
    const int l8 = lane >> 3, lc = (lane & 7) * 8;
#pragma unroll
    for (int i = 0; i < 3; ++i) {
        int cb = w * 3 + i, g = cb / 6, k8 = cb - g * 6;
        int fr = g * 96 + 48 + k8 * 8;
        int r = fr + l8;
        int cs = lc ^ ((r & 7) << 3);
        gld_lds16(Bg + (size_t)(n0 + r) * K + kcol + cs, Bbuf + fr * 64);
    }
    {
        int fr = (w < 4) ? 32 + w * 8 : 96 + (w - 4) * 8;
        int r = fr + l8;
        int cs = lc ^ ((r & 7) << 3);
        gld_lds16(Ag + (size_t)(m0 + r) * K + kcol + cs, Abuf + fr * 64);
    }
}

__device__ __forceinline__ void lda2(const ushort* Abuf, bf16x8 (&a)[2][2], int wr, int Mh, int lane) {
#pragma unroll
    for (int i = 0; i < 2; ++i)
#pragma unroll
        for (int ks = 0; ks < 2; ++ks)
            a[i][ks] = frag_ld(Abuf, wr + Mh * 32 + i * 16, ks * 32, lane);
}
__device__ __forceinline__ void ldb3(const ushort* Bbuf, bf16x8 (&b)[3][2], int wc, int Nh, int lane) {
#pragma unroll
    for (int j = 0; j < 3; ++j)
#pragma unroll
        for (int ks = 0; ks < 2; ++ks)
            b[j][ks] = frag_ld(Bbuf, wc + Nh * 48 + j * 16, ks * 32, lane);
}
__device__ __forceinline__ void mfma6(f32x4 (&acc)[4][6], const bf16x8 (&a)[2][2],
                                      const bf16x8 (&b)[3][2], int Mh, int Nh) {
    __builtin_amdgcn_s_setprio(1);
#pragma unroll
    for (int ks = 0; ks < 2; ++ks)
#pragma unroll
        for (int i = 0; i < 2; ++i)
#pragma unroll
            for (int j = 0; j < 3; ++j)
                acc[Mh * 2 + i][Nh * 3 + j] = __builtin_amdgcn_mfma_f32_16x16x32_bf16(
                    a[i][ks], b[j][ks], acc[Mh * 2 + i][Nh * 3 + j], 0, 0, 0);
    __builtin_amdgcn_s_setprio(0);
}

__global__ __launch_bounds__(512) void gemm_8phase(
    const ushort* __restrict__ A, const ushort* __restrict__ Bt,
    const float* __restrict__ bias, ushort* __restrict__ Cout,
    int M, int N, int K, int reluLimit)
{
    __shared__ __align__(16) ushort lds[65536];

    const int tid = threadIdx.x, w = tid >> 6, lane = tid & 63;
    const int m0 = blockIdx.y * 128, n0 = blockIdx.x * 384;
    const int wr = (w >> 2) * 64, wc = (w & 3) * 96;
    f32x4 acc[4][6] = {};
    const int NT = K / 64;

    stage_G0(A, Bt, lds, lds + 16384, m0, n0, K, 0, w, lane);
    stage_G1(A, Bt, lds, lds + 16384, m0, n0, K, 0, w, lane);

    for (int kt = 0; kt < NT - 1; ++kt) {
        const int p = kt & 1;
        ushort* Acur = lds + p * 8192;
        ushort* Anxt = lds + (p ^ 1) * 8192;
        ushort* Bcur = lds + 16384 + p * 24576;
        ushort* Bnxt = lds + 16384 + (p ^ 1) * 24576;
        const int kc1 = (kt + 1) * 64;
        bf16x8 a[2][2], a2[2][2], b[3][2], b2[3][2];
        VMCNT(4); BAR();
        stage_G0(A, Bt, Anxt, Bnxt, m0, n0, K, kc1, w, lane);
        lda2(Acur, a, wr, 0, lane);
        ldb3(Bcur, b, wc, 0, lane);
        mfma6(acc, a, b, 0, 0);
        VMCNT(5); BAR();
        ldb3(Bcur, b2, wc, 1, lane);
        mfma6(acc, a, b2, 0, 1);
        VMCNT(4); BAR();
        stage_G1(A, Bt, Anxt, Bnxt, m0, n0, K, kc1, w, lane);
        lda2(Acur, a2, wr, 1, lane);
        mfma6(acc, a2, b, 1, 0);
        mfma6(acc, a2, b2, 1, 1);
    }
    {
        const int p = (NT - 1) & 1;
        ushort* Acur = lds + p * 8192;
        ushort* Bcur = lds + 16384 + p * 24576;
        bf16x8 a[2][2], a2[2][2], b[3][2], b2[3][2];
        VMCNT(4); BAR();
        lda2(Acur, a, wr, 0, lane);
        ldb3(Bcur, b, wc, 0, lane);
        mfma6(acc, a, b, 0, 0);
        VMCNT(1); BAR();
        ldb3(Bcur, b2, wc, 1, lane);
        mfma6(acc, a, b2, 0, 1);
        VMCNT(0); BAR();
        lda2(Acur, a2, wr, 1, lane);
        mfma6(acc, a2, b, 1, 0);
        mfma6(acc, a2, b2, 1, 1);
    }

    const int crow = (lane >> 4) * 4, ccol = lane & 15;
#pragma unroll
    for (int nj = 0; nj < 6; ++nj) {
        int col = n0 + wc + nj * 16 + ccol;
        float bv = bias[col];
        bool rl = col < reluLimit;
#pragma unroll
        for (int mi = 0; mi < 4; ++mi) {
#pragma unroll
            for (int rr = 0; rr < 4; ++rr) {
                int row = m0 + wr + mi * 16 + crow + rr;
                float v = acc[mi][nj][rr] + bv;
                if (rl) v = fmaxf(v, 0.f);
                Cout[(size_t)row * N + col] = f2bf(v);
            }
        }
    }
}

// ================= 8-phase GEMM2 (BM=128, BN=128, BK=64, 2 blocks/CU), fragment-hoisted =================
__device__ __forceinline__ void g2_stage_G0(const ushort* __restrict__ Ag, const ushort* __restrict__ Bg,
                                            ushort* Abuf, ushort* Bbuf,
                                            int m0, int n0, int K, int kcol, int w, int lane) {
    const int l8 = lane >> 3, lc = (lane & 7) * 8;
    {
        int rbase = (w < 4) ? w * 8 : 64 + (w - 4) * 8;
        int r = rbase + l8;
        int cs = lc ^ ((r & 7) << 3);
        gld_lds16(Ag + (size_t)(m0 + r) * K + kcol + cs, Abuf + rbase * 64);
    }
    {
        int rbase = (w >> 1) * 32 + (w & 1) * 8;
        int r = rbase + l8;
        int cs = lc ^ ((r & 7) << 3);
        gld_lds16(Bg + (size_t)(n0 + r) * K + kcol + cs, Bbuf + rbase * 64);
    }
}

__device__ __forceinline__ void g2_stage_G1(const ushort* __restrict__ Ag, const ushort* __restrict__ Bg,
                                            ushort* Abuf, ushort* Bbuf,
                                            int m0, int n0, int K, int kcol, int w, int lane) {
    const int l8 = lane >> 3, lc = (lane & 7) * 8;
    {   // B rows {16-31,48-63,80-95,112-127}
        int rbase = 16 + (w >> 1) * 32 + (w & 1) * 8;
        int r = rbase + l8;
        int cs = lc ^ ((r & 7) << 3);
        gld_lds16(Bg + (size_t)(n0 + r) * K + kcol + cs, Bbuf + rbase * 64);
    }
    {   // A rows {32-63, 96-127}
        int rbase = (w < 4) ? 32 + w * 8 : 96 + (w - 4) * 8;
        int r = rbase + l8;
        int cs = lc ^ ((r & 7) << 3);
        gld_lds16(Ag + (size_t)(m0 + r) * K + kcol + cs, Abuf + rbase * 64);
    }
}

__device__ __forceinline__ void g2_ldb(const ushort* Bbuf, bf16x8 (&b)[2], int wc, int Nh, int lane) {
#pragma unroll
    for (int ks = 0; ks < 2; ++ks)
        b[ks] = frag_ld(Bbuf, wc + Nh * 16, ks * 32, lane);
}
__device__ __forceinline__ void g2_mfma(f32x4 (&acc)[4][2], const bf16x8 (&a)[2][2],
                                        const bf16x8 (&b)[2], int Mh, int Nh) {
    __builtin_amdgcn_s_setprio(1);
#pragma unroll
    for (int ks = 0; ks < 2; ++ks)
#pragma unroll
        for (int i = 0; i < 2; ++i)
            acc[Mh * 2 + i][Nh] = __builtin_amdgcn_mfma_f32_16x16x32_bf16(
                a[i][ks], b[ks], acc[Mh * 2 + i][Nh], 0, 0, 0);
    __builtin_amdgcn_s_setprio(0);
}

__global__ __launch_bounds__(512, 4) void gemm2_8phase(
    const ushort* __restrict__ A, const ushort* __restrict__ Bt,
    const float* __restrict__ bias, float* __restrict__ Cout,
    int M, int N, int K)
{
    __shared__ __align__(16) ushort lds[32768];      // 64 KiB

    const int tid = threadIdx.x, w = tid >> 6, lane = tid & 63;
    const int m0 = blockIdx.y * 128, n0 = blockIdx.x * 128;
    const int wr = (w >> 2) * 64, wc = (w & 3) * 32;
    f32x4 acc[4][2] = {};
    const int NT = K / 64;

    g2_stage_G0(A, Bt, lds, lds + 16384, m0, n0, K, 0, w, lane);
    g2_stage_G1(A, Bt, lds, lds + 16384, m0, n0, K, 0, w, lane);

    for (int kt = 0; kt < NT - 1; ++kt) {
        const int p = kt & 1;
        ushort* Acur = lds + p * 8192;
        ushort* Anxt = lds + (p ^ 1) * 8192;
        ushort* Bcur = lds + 16384 + p * 8192;
        ushort* Bnxt = lds + 16384 + (p ^ 1) * 8192;
        const int kc1 = (kt + 1) * 64;
        bf16x8 a[2][2], a2[2][2], b[2], b2[2];
        VMCNT(2); BAR();
        g2_stage_G0(A, Bt, Anxt, Bnxt, m0, n0, K, kc1, w, lane);
        lda2(Acur, a, wr, 0, lane);
        g2_ldb(Bcur, b, wc, 0, lane);
        g2_mfma(acc, a, b, 0, 0);
        VMCNT(3); BAR();
        g2_ldb(Bcur, b2, wc, 1, lane);
        g2_mfma(acc, a, b2, 0, 1);
        VMCNT(2); BAR();
        g2_stage_G1(A, Bt, Anxt, Bnxt, m0, n0, K, kc1, w, lane);
        lda2(Acur, a2, wr, 1, lane);
        g2_mfma(acc, a2, b, 1, 0);
        g2_mfma(acc, a2, b2, 1, 1);
    }
    {
        const int p = (NT - 1) & 1;
        ushort* Acur = lds + p * 8192;
        ushort* Bcur = lds + 16384 + p * 8192;
        bf16x8 a[2][2], a2[2][2], b[2], b2[2];
        VMCNT(2); BAR();
        lda2(Acur, a, wr, 0, lane);
        g2_ldb(Bcur, b, wc, 0, lane);
        g2_mfma(acc, a, b, 0, 0);
        VMCNT(1); BAR();
        g2_ldb(Bcur, b2, wc, 1, lane);
        g2_mfma(acc, a, b2, 0, 1);
        VMCNT(0); BAR();
        lda2(Acur, a2, wr, 1, lane);
        g2_mfma(acc, a2, b, 1, 0);
        g2_mfma(acc, a2, b2, 1, 1);
    }

    const int crow = (lane >> 4) * 4, ccol = lane & 15;
#pragma unroll
    for (int nj = 0; nj < 2; ++nj) {
        int col = n0 + wc + nj * 16 + ccol;
        float bv = bias[col];
#pragma unroll
        for (int mi = 0; mi < 4; ++mi) {
#pragma unroll
            for (int rr = 0; rr < 4; ++rr) {
                int row = m0 + wr + mi * 16 + crow + rr;
                Cout[(size_t)row * N + col] = acc[mi][nj][rr] + bv;
            }
        }
    }
}

// ---------------- chunk_kv: transpose K,V per chunk; St(bf16) = Vt@Kt^T; sK sums ----------------
__global__ __launch_bounds__(256) void chunk_kv_mfma(
    const ushort* __restrict__ out1, ushort* __restrict__ VtG,
    ushort* __restrict__ StB, float* __restrict__ sks)
{
    __shared__ unsigned Tl[64 * 76];
    __shared__ ushort Ktb[64 * 64];
    __shared__ ushort Vtb[64 * 64];
    __shared__ float skp[4][64];
    const int blk = blockIdx.x, c = blk & 31, bh = blk >> 5;
    const int b = bh >> 4, h = bh & 15, t0 = c * CH_;
    const int tid = threadIdx.x, wave = tid >> 6, lane = tid & 63;
    const ushort* kg = out1 + (size_t)(b * T_ + t0) * 3072 + C_ + h * D_;
    const ushort* vg = kg + C_;

#pragma unroll
    for (int it = 0; it < 2; ++it) {
        int i = tid + it * 256, r = i >> 3, sl = i & 7;
        bf16x8 v = *(const bf16x8*)(kg + (size_t)r * 3072 + sl * 8);
        unsigned* dst = &Tl[r * 76 + sl * 8];
        uint4 w0 = { (ushort)v[0], (ushort)v[1], (ushort)v[2], (ushort)v[3] };
        uint4 w1 = { (ushort)v[4], (ushort)v[5], (ushort)v[6], (ushort)v[7] };
        *(uint4*)dst = w0;
        *(uint4*)(dst + 4) = w1;
    }
    __syncthreads();
    {
        int m = tid >> 2, tc = tid & 3;
        bf16x8 va, vb;
        float s = 0.f;
#pragma unroll
        for (int k = 0; k < 8; ++k) {
            ushort u = (ushort)Tl[(tc * 16 + k) * 76 + m];
            va[k] = (short)u; s += bf2f(u);
        }
#pragma unroll
        for (int k = 0; k < 8; ++k) {
            ushort u = (ushort)Tl[(tc * 16 + 8 + k) * 76 + m];
            vb[k] = (short)u; s += bf2f(u);
        }
        skp[tc][m] = s;
        int b0 = (tc * 32) ^ ((m & 7) << 4);
        int b1 = (tc * 32 + 16) ^ ((m & 7) << 4);
        *(bf16x8*)((char*)Ktb + m * 128 + b0) = va;
        *(bf16x8*)((char*)Ktb + m * 128 + b1) = vb;
    }
    __syncthreads();
#pragma unroll
    for (int it = 0; it < 2; ++it) {
        int i = tid + it * 256, r = i >> 3, sl = i & 7;
        bf16x8 v = *(const bf16x8*)(vg + (size_t)r * 3072 + sl * 8);
        unsigned* dst = &Tl[r * 76 + sl * 8];
        uint4 w0 = { (ushort)v[0], (ushort)v[1], (ushort)v[2], (ushort)v[3] };
        uint4 w1 = { (ushort)v[4], (ushort)v[5], (ushort)v[6], (ushort)v[7] };
        *(uint4*)dst = w0;
        *(uint4*)(dst + 4) = w1;
    }
    __syncthreads();
    {
        int d = tid >> 2, tc = tid & 3;
        bf16x8 va, vb;
#pragma unroll
        for (int k = 0; k < 8; ++k) va[k] = (short)(ushort)Tl[(tc * 16 + k) * 76 + d];
#pragma unroll
        for (int k = 0; k < 8; ++k) vb[k] = (short)(ushort)Tl[(tc * 16 + 8 + k) * 76 + d];
        int b0 = (tc * 32) ^ ((d & 7) << 4);
        int b1 = (tc * 32 + 16) ^ ((d & 7) << 4);
        *(bf16x8*)((char*)Vtb + d * 128 + b0) = va;
        *(bf16x8*)((char*)Vtb + d * 128 + b1) = vb;
        ushort* og = VtG + (size_t)blk * 4096 + d * 64 + tc * 16;
        *(bf16x8*)og = va;
        *(bf16x8*)(og + 8) = vb;
    }
    __syncthreads();
    const int wr = wave * 16, g = lane >> 4, ccol = lane & 15;
    f32x4 acc[4] = {};
#pragma unroll
    for (int k0 = 0; k0 < 64; k0 += 32) {
        bf16x8 av = frag_ld(Vtb, wr, k0, lane);
#pragma unroll
        for (int j = 0; j < 4; ++j)
            acc[j] = __builtin_amdgcn_mfma_f32_16x16x32_bf16(av, frag_ld(Ktb, j * 16, k0, lane), acc[j], 0, 0, 0);
    }
    ushort* stg = StB + (size_t)blk * 4096;
#pragma unroll
    for (int j = 0; j < 4; ++j)
#pragma unroll
        for (int r = 0; r < 4; ++r)
            stg[(wr + g * 4 + r) * 64 + j * 16 + ccol] = f2bf(acc[j][r]);
    if (tid < 64)
        sks[(size_t)blk * 64 + tid] = skp[0][tid] + skp[1][tid] + skp[2][tid] + skp[3][tid];
}

// ---------------- parallel exclusive chunk-prefix scan (St bf16) ----------------
__global__ __launch_bounds__(256) void chunk_scan2(const ushort* __restrict__ StB,
                                                   const float* __restrict__ sks,
                                                   ushort* __restrict__ Sbf,
                                                   ushort* __restrict__ skb) {
    if (blockIdx.x < 512) {
        int id = blockIdx.x * 256 + threadIdx.x;
        int bh = id >> 12, e = id & 4095;
        const ushort* p = StB + (size_t)bh * NC_ * 4096 + e;
        ushort* q = Sbf + (size_t)bh * NC_ * 4096 + e;
        float run = 0.f;
        for (int c = 0; c < NC_; ++c) {
            q[(size_t)c * 4096] = f2bf(run);
            run += bf2f(p[(size_t)c * 4096]);
        }
    } else {
        int id2 = (blockIdx.x - 512) * 256 + threadIdx.x;
        int bh = id2 >> 6, m = id2 & 63;
        const float* p = sks + (size_t)bh * NC_ * 64 + m;
        ushort* q = skb + (size_t)bh * NC_ * 64 + m;
        float run = 0.f;
        for (int c = 0; c < NC_; ++c) {
            q[c * 64] = f2bf(run);
            run += p[c * 64];
        }
    }
}

// ---------------- chunk attention (all-MFMA) ----------------
__global__ __launch_bounds__(256) void chunk_attn_mfma(
    const ushort* __restrict__ out1, const ushort* __restrict__ VtG,
    const ushort* __restrict__ Sbf, const ushort* __restrict__ skb,
    ushort* __restrict__ attnBf)
{
    __shared__ ushort Ql[64 * 64];
    __shared__ ushort Kl[64 * 64];
    __shared__ ushort Vl[64 * 64];
    __shared__ ushort Al[64 * 64];
    __shared__ ushort Sl[80 * 64];
    const int blk = blockIdx.x, c = blk & 31, bh = blk >> 5;
    const int b = bh >> 4, h = bh & 15, t0 = c * CH_;
    const int tid = threadIdx.x, wave = tid >> 6, lane = tid & 63;
    const ushort* qg  = out1 + (size_t)(b * T_ + t0) * 3072 + h * D_;
    const ushort* kg  = qg + C_;
    const ushort* vtg = VtG + (size_t)blk * 4096;
    const ushort* sbg = Sbf + (size_t)blk * 4096;
#pragma unroll
    for (int it = 0; it < 2; ++it) {
        int i = tid + it * 256, r = i >> 3, sl = i & 7;
        int lo = (sl * 16) ^ ((r & 7) << 4);
        *(bf16x8*)((char*)Ql + r * 128 + lo) = *(const bf16x8*)(qg + (size_t)r * 3072 + sl * 8);
        *(bf16x8*)((char*)Kl + r * 128 + lo) = *(const bf16x8*)(kg + (size_t)r * 3072 + sl * 8);
        *(bf16x8*)((char*)Vl + r * 128 + lo) = *(const bf16x8*)(vtg + r * 64 + sl * 8);
        *(bf16x8*)((char*)Sl + r * 128 + lo) = *(const bf16x8*)(sbg + r * 64 + sl * 8);
    }
    if (tid < 8)
        *(bf16x8*)((char*)Sl + 64 * 128 + tid * 16) = *(const bf16x8*)(skb + (size_t)blk * 64 + tid * 8);
    __syncthreads();

    const int wr = wave * 16, g = lane >> 4, ccol = lane & 15;
    f32x4 accA[4] = {};
#pragma unroll
    for (int k0 = 0; k0 < 64; k0 += 32) {
        bf16x8 aq = frag_ld(Ql, wr, k0, lane);
#pragma unroll
        for (int j = 0; j < 4; ++j)
            accA[j] = __builtin_amdgcn_mfma_f32_16x16x32_bf16(aq, frag_ld(Kl, j * 16, k0, lane), accA[j], 0, 0, 0);
    }
    float rsum[4] = {0.f, 0.f, 0.f, 0.f};
#pragma unroll
    for (int j = 0; j < 4; ++j) {
#pragma unroll
        for (int r = 0; r < 4; ++r) {
            int tl = wr + g * 4 + r, sl2 = j * 16 + ccol;
            float v = (sl2 <= tl) ? accA[j][r] : 0.f;
            rsum[r] += v;
            *(ushort*)((char*)Al + tl * 128 + ((sl2 * 2) ^ ((tl & 7) << 4))) = f2bf(v);
        }
    }
#pragma unroll
    for (int r = 0; r < 4; ++r) {
        rsum[r] += __shfl_xor(rsum[r], 1);
        rsum[r] += __shfl_xor(rsum[r], 2);
        rsum[r] += __shfl_xor(rsum[r], 4);
        rsum[r] += __shfl_xor(rsum[r], 8);
    }
    f32x4 accC[4] = {};
    f32x4 accE = {};
#pragma unroll
    for (int k0 = 0; k0 < 64; k0 += 32) {
        bf16x8 aa = frag_ld(Al, wr, k0, lane);
#pragma unroll
        for (int j = 0; j < 4; ++j)
            accC[j] = __builtin_amdgcn_mfma_f32_16x16x32_bf16(aa, frag_ld(Vl, j * 16, k0, lane), accC[j], 0, 0, 0);
    }
#pragma unroll
    for (int k0 = 0; k0 < 64; k0 += 32) {
        bf16x8 aq = frag_ld(Ql, wr, k0, lane);
#pragma unroll
        for (int j = 0; j < 4; ++j)
            accC[j] = __builtin_amdgcn_mfma_f32_16x16x32_bf16(aq, frag_ld(Sl, j * 16, k0, lane), accC[j], 0, 0, 0);
        accE = __builtin_amdgcn_mfma_f32_16x16x32_bf16(aq, frag_ld(Sl, 64, k0, lane), accE, 0, 0, 0);
    }
    ushort* og = attnBf + (size_t)(b * T_ + t0) * C_ + h * D_;
#pragma unroll
    for (int r = 0; r < 4; ++r) {
        float nq = __shfl(accE[r], (lane & 48));
        float inv = 1.f / (nq + rsum[r] + 1e-6f);
        int tl = wr + g * 4 + r;
#pragma unroll
        for (int j = 0; j < 4; ++j)
            og[(size_t)tl * C_ + j * 16 + ccol] = f2bf(accC[j][r] * inv);
    }
}

extern "C" void kernel_launch(void* const* d_in, const int* in_sizes, int n_in,
                              void* d_out, int out_size, void* d_ws, size_t ws_size,
                              hipStream_t stream) {
    (void)in_sizes; (void)n_in; (void)out_size; (void)ws_size;
    const float* x    = (const float*)d_in[0];
    const float* Wqkv = (const float*)d_in[1];
    const float* bqkv = (const float*)d_in[2];
    const float* Wout = (const float*)d_in[3];
    const float* bout = (const float*)d_in[4];
    const float* proj = (const float*)d_in[5];
    float* out = (float*)d_out;
    char* ws = (char*)d_ws;

    ushort* Wbt    = (ushort*)(ws);                 // 6 MB
    ushort* xbf    = (ushort*)(ws + (6ull  << 20)); // 8 MB
    ushort* WoutBf = (ushort*)(ws + (14ull << 20)); // 2 MB
    ushort* attnBf = (ushort*)(ws + (16ull << 20)); // 8 MB
    float*  bbig   = (float*) (ws + (24ull << 20)); // 12 KB
    ushort* out1   = (ushort*)(ws + (25ull << 20)); // 24 MB (bf16 q'|k'|v)
    ushort* VtG    = (ushort*)(ws + (49ull << 20)); // 8 MB
    ushort* StB    = (ushort*)(ws + (57ull << 20)); // 8 MB (bf16)
    ushort* Sbf    = (ushort*)(ws + (65ull << 20)); // 8 MB
    float*  sks    = (float*) (ws + (73ull << 20)); // 256 KB
    ushort* skb    = (ushort*)(ws + (74ull << 20)); // 128 KB

    prep_all<<<NPREP_, 256, 0, stream>>>(x, Wqkv, bqkv, Wout, proj,
                                         Wbt, xbf, WoutBf, bbig);
    gemm_8phase<<<dim3(8, 32), 512, 0, stream>>>(xbf, Wbt, bbig, out1,
                                                 4096, 3072, 1024, 2048);
    chunk_kv_mfma<<<1024, 256, 0, stream>>>(out1, VtG, StB, sks);
    chunk_scan2<<<520, 256, 0, stream>>>(StB, sks, Sbf, skb);
    chunk_attn_mfma<<<1024, 256, 0, stream>>>(out1, VtG, Sbf, skb, attnBf);
    gemm2_8phase<<<dim3(8, 32), 512, 0, stream>>>(attnBf, WoutBf, bout, out,
                                                  4096, 1024, 1024);
}